// Round 4
// baseline (99.650 us; speedup 1.0000x reference)
//
#include <hip/hip_runtime.h>
#include <stdint.h>

// InterGate: B=1, C=192, H=W=96.  Flash-attention formulation:
//   Q = (latent*w4)^T, K = refined^T, V = (latent*w4)^T   (all [9216, 192])
//   out = refined*w5 + (softmax(Q K^T) V)^T
// Round-4 structure (on top of r3's 32x32x16 swapped-QK design):
//   * 64 queries/wave (2 q-subtiles): every K/V LDS fragment read feeds 2
//     MFMAs -> LDS read traffic halves (was the bottleneck: 1 read : 1 MFMA)
//   * V rows stored in prep in the S' C/D key order (16T+(i&3)+8(i>>2)+4h),
//     so the P B-frag is exactly the cvt_pk word sequence: the cross-half
//     shfl/bpermute exchange is GONE; P never leaves registers
//   * Q pre-scaled by log2e in prep; P = v_exp_f32(S' - 25*log2e) directly
//   * no-max softmax (validated r2/r3), KS=7 key splits, plain-sum combine

#define NQ 9216
#define NC 192
#define FR 1769472      // 9216*192 elements per fragment array
#define LOG2E 1.4426950408889634f
#define M0L 36.06737602f   // 25 * log2(e)

typedef short    bfrag  __attribute__((ext_vector_type(8)));   // 8 bf16
typedef _Float16 hfrag  __attribute__((ext_vector_type(8)));   // 8 f16
typedef short    sfrag4 __attribute__((ext_vector_type(4)));   // 4 bf16 (8B)
typedef float    facc16 __attribute__((ext_vector_type(16)));  // 32x32 accum

__device__ __forceinline__ short f2bf(float x) {
    uint32_t u = __builtin_bit_cast(uint32_t, x);
    u = (u + 0x7fffu + ((u >> 16) & 1u)) >> 16;
    return (short)u;
}
__device__ __forceinline__ float bf2f(short s) {
    uint32_t u = ((uint32_t)(uint16_t)s) << 16;
    return __builtin_bit_cast(float, u);
}
__device__ __forceinline__ int cvtpk_bf16(float lo, float hi) {
    int r;
    asm("v_cvt_pk_bf16_f32 %0, %1, %2" : "=v"(r) : "v"(lo), "v"(hi));
    return r;
}
__device__ __forceinline__ float exp2_raw(float x) {   // 2^x via v_exp_f32
    float r;
    asm("v_exp_f32 %0, %1" : "=v"(r) : "v"(x));
    return r;
}
__device__ __forceinline__ bfrag words_to_frag(int w0, int w1, int w2, int w3) {
    union { int i[4]; bfrag f; } u;
    u.i[0] = w0; u.i[1] = w1; u.i[2] = w2; u.i[3] = w3;
    return u.f;
}
__device__ __forceinline__ void gload_lds16(const void* g, void* l) {
    __builtin_amdgcn_global_load_lds(
        (__attribute__((address_space(1))) const void*)(uintptr_t)g,
        (__attribute__((address_space(3))) void*)(uint32_t)(uintptr_t)l,
        16, 0, 0);
}

// ---------------------------------------------------------------------------
// Prep: fragment-ordered arrays for 32x32x16 (l32=lane&31, h=lane>>5).
// Qf (f16, B-frag, pre-scaled by log2e):
//   [qw(288)][t(12)][lane][i8] = log2e * Q[qw*32+l32][t*16+h*8+i]
// KV per 64-key group kg (24576 shorts = 48KB):
//  [0]     K (f16, A-frag): [n2(2)][t(12)][lane][i8] = K[kg*64+n2*32+l32][t*16+h*8+i]
//  [12288] V (bf16, A-frag of V^T, PERMUTED key order):
//          [ksp(4)][cb(6)][lane][i8] = V[kg*64+ksp*16+(i&3)+8*(i>>2)+4*h][cb*32+l32]
//          (matches the 32x32 C/D row order of S' so P needs no exchange)
// ---------------------------------------------------------------------------
__global__ __launch_bounds__(256) void InterGate_prep(
    const float* __restrict__ latent, const float* __restrict__ refined,
    const float* __restrict__ w4,
    short* __restrict__ Qf, short* __restrict__ KV)
{
    const int wid  = blockIdx.x * 4 + (threadIdx.x >> 6);
    const int lane = threadIdx.x & 63;
    const int l32  = lane & 31, h = lane >> 5;

    if (wid < 3456) {                       // Q fragments (latent*w4*log2e), f16
        const int qw = wid / 12, t = wid % 12;
        const int q  = qw * 32 + l32;
        const int c0 = t * 16 + h * 8;
        hfrag hv;
        #pragma unroll
        for (int i = 0; i < 8; i++) {
            size_t idx = (size_t)(c0 + i) * NQ + q;
            hv[i] = (_Float16)(latent[idx] * w4[idx] * LOG2E);
        }
        *(hfrag*)(void*)(Qf + ((size_t)wid * 64 + lane) * 8) = hv;
    } else if (wid < 6912) {                // K fragments (refined), f16
        const int u  = wid - 3456;
        const int kg = u / 24, r = u % 24;
        const int n2 = r / 12, t = r % 12;
        const int key = kg * 64 + n2 * 32 + l32;
        const int c0  = t * 16 + h * 8;
        hfrag hv;
        #pragma unroll
        for (int i = 0; i < 8; i++) {
            size_t idx = (size_t)(c0 + i) * NQ + key;
            hv[i] = (_Float16)refined[idx];
        }
        *(hfrag*)(void*)(KV + (size_t)kg * 24576 + ((n2 * 12 + t) * 64 + lane) * 8) = hv;
    } else {                                // V fragments (latent*w4), bf16, permuted
        const int u  = wid - 6912;
        const int kg = u / 24, r = u % 24;
        const int t  = r / 6, cb = r % 6;
        const int c  = cb * 32 + l32;
        const int k0 = kg * 64 + t * 16 + 4 * h;
        bfrag bv;
        #pragma unroll
        for (int i = 0; i < 8; i++) {
            const int row = k0 + (i & 3) + 8 * (i >> 2);
            size_t idx = (size_t)c * NQ + row;
            bv[i] = f2bf(latent[idx] * w4[idx]);
        }
        *(bfrag*)(void*)(KV + (size_t)kg * 24576 + 12288 + ((t * 6 + cb) * 64 + lane) * 8) = bv;
    }
}

// ---------------------------------------------------------------------------
// Flash: grid (36 q-tiles of 256, KS key-splits), 4 waves x 64 q (two
// 32-q subtiles), 64-key tiles double-buffered (96KB LDS), 1 block/CU.
// Per tile per wave: 24 K-reads -> 48 QK MFMAs, 24 V-reads -> 48 PV MFMAs.
// ---------------------------------------------------------------------------
__global__ __launch_bounds__(256, 1) void InterGate_flash(
    const short* __restrict__ Qf, const short* __restrict__ KV,
    short* __restrict__ Opart, float* __restrict__ l_ws, int KS)
{
    __shared__ __align__(16) short kv[2][24576];   // 2 x 48KB: K(f16) | V(bf16)

    const int tid  = threadIdx.x;
    const int lane = tid & 63, w = tid >> 6;
    const int l32  = lane & 31, h = lane >> 5;
    const int qt   = blockIdx.x, ks = blockIdx.y;

    const int base = 144 / KS, rem = 144 % KS;
    const int start = ks * base + (ks < rem ? ks : rem);
    const int cnt   = base + (ks < rem ? 1 : 0);

    // two Q B-frag subtiles in registers (96 VGPR)
    const int qw = qt * 8 + w * 2;
    hfrag qa[12], qb[12];
    #pragma unroll
    for (int t = 0; t < 12; t++) {
        qa[t] = *(const hfrag*)(const void*)(Qf + (((size_t)qw * 12 + t) * 64 + lane) * 8);
        qb[t] = *(const hfrag*)(const void*)(Qf + (((size_t)(qw + 1) * 12 + t) * 64 + lane) * 8);
    }

    facc16 OA[6], OB[6];
    #pragma unroll
    for (int cb = 0; cb < 6; cb++) {
        #pragma unroll
        for (int j = 0; j < 16; j++) { OA[cb][j] = 0.f; OB[cb][j] = 0.f; }
    }
    float lsA = 0.f, lsB = 0.f;

    {   // stage tile 0 (12 chunks of 1KB per wave)
        const char* src = (const char*)(KV + (size_t)start * 24576) + w * 12288 + lane * 16;
        char* dst = (char*)&kv[0][0] + w * 12288;
        #pragma unroll
        for (int j = 0; j < 12; j++)
            gload_lds16(src + j * 1024, dst + j * 1024);
    }

    for (int kt = 0; kt < cnt; kt++) {
        __syncthreads();                       // tile kt staged (drains vmem)
        const int cur = kt & 1;
        if (kt + 1 < cnt) {                    // prefetch next tile
            const char* src = (const char*)(KV + (size_t)(start + kt + 1) * 24576) + w * 12288 + lane * 16;
            char* dst = (char*)&kv[cur ^ 1][0] + w * 12288;
            #pragma unroll
            for (int j = 0; j < 12; j++)
                gload_lds16(src + j * 1024, dst + j * 1024);
        }
        const short* kb = &kv[cur][0];

        #pragma unroll
        for (int n2 = 0; n2 < 2; n2++) {
            // ---- S' = K Q: 32 keys x 64 queries (each K-frag feeds 2 MFMAs) ----
            facc16 S0, S1;
            #pragma unroll
            for (int j = 0; j < 16; j++) { S0[j] = 0.f; S1[j] = 0.f; }
            #pragma unroll
            for (int t = 0; t < 12; t++) {
                hfrag kf = *(const hfrag*)(const void*)(kb + (n2 * 12 + t) * 512 + lane * 8);
                S0 = __builtin_amdgcn_mfma_f32_32x32x16_f16(kf, qa[t], S0, 0, 0, 0);
                S1 = __builtin_amdgcn_mfma_f32_32x32x16_f16(kf, qb[t], S1, 0, 0, 0);
            }
            // S' layout: key = (j&3)+8*(j>>2)+4*h (lane-local), q = l32

            // ---- P = 2^(S' - M0L); pack; tree-sum into l ----
            float pa[16], pb[16];
            #pragma unroll
            for (int j = 0; j < 16; j++) {
                pa[j] = exp2_raw(S0[j] - M0L);
                pb[j] = exp2_raw(S1[j] - M0L);
            }
            lsA += (((pa[0]+pa[1])+(pa[2]+pa[3]))+((pa[4]+pa[5])+(pa[6]+pa[7])))
                 + (((pa[8]+pa[9])+(pa[10]+pa[11]))+((pa[12]+pa[13])+(pa[14]+pa[15])));
            lsB += (((pb[0]+pb[1])+(pb[2]+pb[3]))+((pb[4]+pb[5])+(pb[6]+pb[7])))
                 + (((pb[8]+pb[9])+(pb[10]+pb[11]))+((pb[12]+pb[13])+(pb[14]+pb[15])));
            int cpA[8], cpB[8];
            #pragma unroll
            for (int a = 0; a < 8; a++) {
                cpA[a] = cvtpk_bf16(pa[2 * a], pa[2 * a + 1]);
                cpB[a] = cvtpk_bf16(pb[2 * a], pb[2 * a + 1]);
            }

            // ---- O^T += V^T P (V rows pre-permuted; P frag = cp words) ----
            #pragma unroll
            for (int T = 0; T < 2; T++) {
                bfrag pfA = words_to_frag(cpA[4*T], cpA[4*T+1], cpA[4*T+2], cpA[4*T+3]);
                bfrag pfB = words_to_frag(cpB[4*T], cpB[4*T+1], cpB[4*T+2], cpB[4*T+3]);
                const int ksp = n2 * 2 + T;
                #pragma unroll
                for (int cb = 0; cb < 6; cb++) {
                    bfrag vf = *(const bfrag*)(const void*)(kb + 12288 + (ksp * 6 + cb) * 512 + lane * 8);
                    OA[cb] = __builtin_amdgcn_mfma_f32_32x32x16_bf16(vf, pfA, OA[cb], 0, 0, 0);
                    OB[cb] = __builtin_amdgcn_mfma_f32_32x32x16_bf16(vf, pfB, OB[cb], 0, 0, 0);
                }
            }
        }
    }

    // ---- epilogue: Opart[ks][q][c] (bf16, unnormalized) + l per query ----
    const int q0 = qt * 256 + w * 64 + l32;
    short* rowA = Opart + ((size_t)ks * NQ + q0) * NC;
    short* rowB = rowA + (size_t)32 * NC;
    #pragma unroll
    for (int cb = 0; cb < 6; cb++) {
        #pragma unroll
        for (int g = 0; g < 4; g++) {
            const int c0 = cb * 32 + 8 * g + 4 * h;
            sfrag4 sa, sb;
            #pragma unroll
            for (int r = 0; r < 4; r++) { sa[r] = f2bf(OA[cb][4*g+r]); sb[r] = f2bf(OB[cb][4*g+r]); }
            *(sfrag4*)(void*)(rowA + c0) = sa;
            *(sfrag4*)(void*)(rowB + c0) = sb;
        }
    }
    float la = lsA + __shfl_xor(lsA, 32);
    float lb = lsB + __shfl_xor(lsB, 32);
    if (h == 0) {
        l_ws[(size_t)ks * NQ + q0]      = la;
        l_ws[(size_t)ks * NQ + q0 + 32] = lb;
    }
}

// ---------------------------------------------------------------------------
// Combine: sum KS partials (common scale), normalize, transpose via LDS,
// fused epilogue out = refined*w5 + ctx.  288 blocks x 32 queries.
// ---------------------------------------------------------------------------
__global__ __launch_bounds__(256) void InterGate_combine(
    const short* __restrict__ Opart, const float* __restrict__ l_ws,
    const float* __restrict__ refined, const float* __restrict__ w5,
    float* __restrict__ out, int KS)
{
    __shared__ float ctx[32][193];
    __shared__ float sInv[32];
    const int qt = blockIdx.x, tid = threadIdx.x;

    if (tid < 32) {
        const int q = qt * 32 + tid;
        float L = 0.f;
        for (int ks = 0; ks < KS; ks++) L += l_ws[(size_t)ks * NQ + q];
        sInv[tid] = 1.f / L;
    }
    __syncthreads();

    for (int u = tid; u < 768; u += 256) {
        const int ql = u / 24, c0 = (u % 24) * 8;
        float acc[8] = {0.f, 0.f, 0.f, 0.f, 0.f, 0.f, 0.f, 0.f};
        for (int ks = 0; ks < KS; ks++) {
            bfrag pk = *(const bfrag*)(const void*)&Opart[((size_t)ks * NQ + qt * 32 + ql) * NC + c0];
            #pragma unroll
            for (int j = 0; j < 8; j++) acc[j] += bf2f(pk[j]);
        }
        const float inv = sInv[ql];
        #pragma unroll
        for (int j = 0; j < 8; j++) ctx[ql][c0 + j] = acc[j] * inv;
    }
    __syncthreads();

    for (int u = tid; u < 6144; u += 256) {
        const int c = u / 32, qx = u % 32;
        size_t o = (size_t)c * NQ + qt * 32 + qx;
        out[o] = refined[o] * w5[o] + ctx[qx][c];
    }
}

// ---------------------------------------------------------------------------
extern "C" void kernel_launch(void* const* d_in, const int* in_sizes, int n_in,
                              void* d_out, int out_size, void* d_ws, size_t ws_size,
                              hipStream_t stream)
{
    (void)in_sizes; (void)n_in; (void)out_size;
    const float* latent  = (const float*)d_in[0];
    const float* refined = (const float*)d_in[1];
    const float* w4      = (const float*)d_in[2];
    const float* w5      = (const float*)d_in[3];
    float* out = (float*)d_out;

    short* Qf = (short*)d_ws;
    short* KV = Qf + FR;                     // 2*FR shorts (K|V per 64-key group)
    const size_t basebytes = (size_t)3 * FR * 2;

    const int opts[4] = {7, 4, 2, 1};
    int KS = 0;
    for (int i = 0; i < 4; i++) {
        size_t need = basebytes + (size_t)opts[i] * ((size_t)NQ * NC * 2 + (size_t)NQ * 4);
        if (need <= ws_size) { KS = opts[i]; break; }
    }
    if (KS == 0) return;

    short* Opart = (short*)((char*)d_ws + basebytes);
    float* l_ws  = (float*)((char*)d_ws + basebytes + (size_t)KS * NQ * NC * 2);

    InterGate_prep<<<2592, 256, 0, stream>>>(latent, refined, w4, Qf, KV);
    dim3 fg(36, KS);
    InterGate_flash<<<fg, 256, 0, stream>>>(Qf, KV, Opart, l_ws, KS);
    InterGate_combine<<<288, 256, 0, stream>>>(Opart, l_ws, refined, w5, out, KS);
}